// Round 7
// baseline (511.909 us; speedup 1.0000x reference)
//
#include <hip/hip_runtime.h>
#include <stdint.h>

// ---------------------------------------------------------------------------
// VQ-VAE forward on MI355X (gfx950).  Round 9 (resubmit — r9 bench was an
// infra failure: "container failed twice"; audit: uniform barriers + monotone
// vmcnt => no deadlock possible; race would show as passed:false, not infra).
// r4 insight (kept): np's dists = fl(fl(s1+s2) - 2*G) fp32 grid + first-index
// tie-break reproduced bit-exactly; encoder fp16-split MFMA, z-layer fp32
// VALU, decoder bf16 MFMA.
// r5 (kept): LDS-staged register-tiled VQ (934 -> <126 us).
// r7 (kept): identity block map; XOR in-slot staging/read permutation -> 0
// bank conflicts, fragments bit-identical.
// r8 (kept): double-buffered 2-phase prefetch.
// r9: r8's __syncthreads emitted vmcnt(0) each half-step -> the just-issued
// STAGE had only COMPUTE (~300cy) to cover ~600-900cy HBM latency; drain
// stall remained (MfmaUtil 38 vs ~45 bound).  T4 counted-vmcnt schedule:
// raw s_barrier + s_waitcnt vmcnt(NLD) ("memory" clobber), so each STAGE
// gets a full half-step in flight and is never drained to 0 in steady state.
//   iter: STAGE(1,k+32); vm(N); bar; COMP(0); bar; STAGE(0,k+64); vm(N|0);
//         bar; COMP(1); bar          (K%64==0 for all dispatches)
// Race audit: overwrite-after-read ordered by the post-COMPUTE barriers;
// read-after-write by counted wait (per-thread) + pre-COMPUTE barrier (all
// threads).  Sync-only change -> bit-exact output.
// ---------------------------------------------------------------------------

typedef unsigned int u32;
typedef __attribute__((ext_vector_type(8))) short   short8;  // 8 x 16-bit
typedef __attribute__((ext_vector_type(8))) _Float16 half8;
typedef __attribute__((ext_vector_type(4))) float   floatx4; // MFMA C/D

__device__ __forceinline__ unsigned short f2bf(float f) {    // RNE fp32->bf16
    u32 u = __float_as_uint(f);
    u += 0x7fffu + ((u >> 16) & 1u);
    return (unsigned short)(u >> 16);
}
__device__ __forceinline__ float bf2f(unsigned short h) {
    return __uint_as_float(((u32)h) << 16);
}
__device__ __forceinline__ unsigned short f2h(float f) {     // RNE fp32->fp16
    _Float16 h = (_Float16)f;
    return __builtin_bit_cast(unsigned short, h);
}
__device__ __forceinline__ float h2f(unsigned short u) {
    return (float)__builtin_bit_cast(_Float16, u);
}

#define GLDS16(gp, lp) __builtin_amdgcn_global_load_lds(                      \
    (const __attribute__((address_space(1))) u32*)(const void*)(gp),          \
    (__attribute__((address_space(3))) u32*)(void*)(lp), 16, 0, 0)

// fp32 -> (hi, lo) fp16 split (encoder operands)
__global__ __launch_bounds__(256)
void cvt_split_h(const float* __restrict__ in, unsigned short* __restrict__ hi,
                 unsigned short* __restrict__ lo, int n)
{
    int i = (blockIdx.x * 256 + threadIdx.x) * 4;
    if (i >= n) return;
    const float4 v = *(const float4*)(in + i);
    unsigned short a = f2h(v.x), b = f2h(v.y), c = f2h(v.z), d = f2h(v.w);
    *(ushort4*)(hi + i) = make_ushort4(a, b, c, d);
    *(ushort4*)(lo + i) = make_ushort4(f2h(v.x - h2f(a)), f2h(v.y - h2f(b)),
                                       f2h(v.z - h2f(c)), f2h(v.w - h2f(d)));
}

// fp32 -> bf16 (decoder weights)
__global__ __launch_bounds__(256)
void cvt1(const float* __restrict__ in, unsigned short* __restrict__ hi, int n)
{
    int i = (blockIdx.x * 256 + threadIdx.x) * 4;
    if (i >= n) return;
    const float4 v = *(const float4*)(in + i);
    *(ushort4*)(hi + i) = make_ushort4(f2bf(v.x), f2bf(v.y), f2bf(v.z), f2bf(v.w));
}

// s2[c] = np.sum(codebook[c]**2) with numpy's EXACT pairwise-64 order:
// 8 accumulators over strided elements, then ((r0+r1)+(r2+r3))+((r4+r5)+(r6+r7))
__global__ __launch_bounds__(256)
void prep_s2(const float* __restrict__ cb, float* __restrict__ s2)
{
    int c = blockIdx.x * 256 + threadIdx.x;   // grid 4 -> 1024 codes
    const float* a = cb + (size_t)c * 64;
    float r[8];
#pragma unroll
    for (int j = 0; j < 8; ++j) r[j] = __fmul_rn(a[j], a[j]);
#pragma unroll
    for (int b = 1; b < 8; ++b)
#pragma unroll
        for (int j = 0; j < 8; ++j)
            r[j] = __fadd_rn(r[j], __fmul_rn(a[8 * b + j], a[8 * b + j]));
    float s = __fadd_rn(__fadd_rn(__fadd_rn(r[0], r[1]), __fadd_rn(r[2], r[3])),
                        __fadd_rn(__fadd_rn(r[4], r[5]), __fadd_rn(r[6], r[7])));
    s2[c] = s;
}

// transpose z_w [256,512] -> zwT [512,256] for coalesced VALU GEMM loads
__global__ __launch_bounds__(256)
void transpose_zw(const float* __restrict__ zw, float* __restrict__ zwT)
{
    int i = blockIdx.x * 256 + threadIdx.x;   // grid 512 -> 131072
    int k = i >> 8, c = i & 255;
    zwT[i] = zw[c * 512 + k];
}

// z = h1 @ z_w^T + z_b in fp32 VALU (pristine weights, 4-phase accumulators).
// 8 rows x 256 cols per block; h1 tile staged in LDS.
__global__ __launch_bounds__(256)
void zgemm(const float* __restrict__ h1, const float* __restrict__ zwT,
           const float* __restrict__ zb, float* __restrict__ zf)
{
    __shared__ float sh[8 * 512];
    const int t = threadIdx.x;
    const int r0 = blockIdx.x * 8;            // grid 1024 -> 8192 rows
    const float4* src = (const float4*)(h1 + (size_t)r0 * 512);
    float4* dst = (float4*)sh;
#pragma unroll
    for (int i = 0; i < 4; ++i) dst[t + i * 256] = src[t + i * 256];
    __syncthreads();

    const int col = t;                        // N = 256
    float acc[8][4];
#pragma unroll
    for (int r = 0; r < 8; ++r)
#pragma unroll
        for (int p = 0; p < 4; ++p) acc[r][p] = 0.f;

    for (int k = 0; k < 512; k += 4) {
        float w0 = zwT[(k + 0) * 256 + col];
        float w1 = zwT[(k + 1) * 256 + col];
        float w2 = zwT[(k + 2) * 256 + col];
        float w3 = zwT[(k + 3) * 256 + col];
#pragma unroll
        for (int r = 0; r < 8; ++r) {
            float4 hv = *(const float4*)(sh + r * 512 + k);
            acc[r][0] += hv.x * w0;
            acc[r][1] += hv.y * w1;
            acc[r][2] += hv.z * w2;
            acc[r][3] += hv.w * w3;
        }
    }
    const float bv = zb[col];
#pragma unroll
    for (int r = 0; r < 8; ++r) {
        float s = ((acc[r][0] + acc[r][1]) + (acc[r][2] + acc[r][3])) + bv;
        zf[(size_t)(r0 + r) * 256 + col] = s;
    }
}

// VQ with np's exact fp32 distance profile:
//   dist_j = fl( fl(s1 + s2_j) - 2*G_j ),  s1 = np-pairwise-64 of fl(z_i^2)
// argmin strict-< ascending (np first-index tie-break, incl. exact fp32 ties).
__global__ __launch_bounds__(256)
void vq_kernel(const float* __restrict__ z, const float* __restrict__ cb,
               const float* __restrict__ s2g, unsigned short* __restrict__ zq)
{
    __shared__ __align__(16) float shz[64 * 68];
    __shared__ __align__(16) float shc[64 * 68];
    __shared__ __align__(16) float shs2[1024];
    __shared__ float shs1[64];

    const int t  = threadIdx.x;
    const int tc = t & 15;        // code lane 0..15
    const int tr = t >> 4;        // row group 0..15 (4 rows each)
    const int r0 = blockIdx.x * 64;   // grid 512 -> 32768 rows

    // stage s2 table (1024 f32)
    *(float4*)(shs2 + t * 4) = *(const float4*)(s2g + t * 4);
    // stage 64 z-rows: thread t -> row t>>2, float4 slots (t&3)+4k
    {
        const int zr = t >> 2, f0 = t & 3;
        const float* src = z + (size_t)(r0 + zr) * 64;
        float* dst = shz + zr * 68;
#pragma unroll
        for (int k = 0; k < 4; ++k) {
            const int f = f0 + 4 * k;
            *(float4*)(dst + f * 4) = *(const float4*)(src + f * 4);
        }
    }
    __syncthreads();

    // s1 per row: numpy pairwise order, contraction-proof (wave 0 only)
    if (t < 64) {
        const float* a = shz + t * 68;
        float r[8];
#pragma unroll
        for (int j = 0; j < 8; ++j) r[j] = __fmul_rn(a[j], a[j]);
#pragma unroll
        for (int b = 1; b < 8; ++b)
#pragma unroll
            for (int j = 0; j < 8; ++j)
                r[j] = __fadd_rn(r[j], __fmul_rn(a[8 * b + j], a[8 * b + j]));
        shs1[t] = __fadd_rn(
            __fadd_rn(__fadd_rn(r[0], r[1]), __fadd_rn(r[2], r[3])),
            __fadd_rn(__fadd_rn(r[4], r[5]), __fadd_rn(r[6], r[7])));
    }
    __syncthreads();

    float s1r[4];
#pragma unroll
    for (int i = 0; i < 4; ++i) s1r[i] = shs1[tr * 4 + i];

    float bestd[4];
    int   bestj[4];
#pragma unroll
    for (int i = 0; i < 4; ++i) { bestd[i] = 3.4e38f; bestj[i] = 0; }

    for (int cc = 0; cc < 16; ++cc) {
        // stage code chunk cc (codes cc*64 .. cc*64+63)
        {
            const int cr = t >> 2, f0 = t & 3;
            const float* src = cb + (size_t)(cc * 64 + cr) * 64;
            float* dst = shc + cr * 68;
#pragma unroll
            for (int k = 0; k < 4; ++k) {
                const int f = f0 + 4 * k;
                *(float4*)(dst + f * 4) = *(const float4*)(src + f * 4);
            }
        }
        __syncthreads();

        // 4 rows x 4 codes, accumulators a0..a3 per pair (same order as r4)
        float acc[4][4][4];
#pragma unroll
        for (int i = 0; i < 4; ++i)
#pragma unroll
            for (int q = 0; q < 4; ++q)
#pragma unroll
                for (int p = 0; p < 4; ++p) acc[i][q][p] = 0.f;

#pragma unroll 4
        for (int d = 0; d < 16; ++d) {
            float4 zv[4], cv[4];
#pragma unroll
            for (int i = 0; i < 4; ++i)
                zv[i] = *(const float4*)(shz + (tr * 4 + i) * 68 + d * 4);
#pragma unroll
            for (int q = 0; q < 4; ++q)
                cv[q] = *(const float4*)(shc + (q * 16 + tc) * 68 + d * 4);
#pragma unroll
            for (int i = 0; i < 4; ++i)
#pragma unroll
                for (int q = 0; q < 4; ++q) {
                    acc[i][q][0] += zv[i].x * cv[q].x;
                    acc[i][q][1] += zv[i].y * cv[q].y;
                    acc[i][q][2] += zv[i].z * cv[q].z;
                    acc[i][q][3] += zv[i].w * cv[q].w;
                }
        }

#pragma unroll
        for (int q = 0; q < 4; ++q) {
            const int j = cc * 64 + q * 16 + tc;
            const float s2v = shs2[j];
#pragma unroll
            for (int i = 0; i < 4; ++i) {
                const float g  = (acc[i][q][0] + acc[i][q][1])
                               + (acc[i][q][2] + acc[i][q][3]);
                const float t1 = __fadd_rn(s1r[i], s2v);     // np: (s1+s2) first
                const float dist = __fadd_rn(t1, -(2.0f * g)); // then - 2*G
                if (dist < bestd[i]) { bestd[i] = dist; bestj[i] = j; }
            }
        }
        __syncthreads();
    }

    // reduce across the 16 tc-lanes (lexicographic min on (dist, j));
    // after the xor-butterfly ALL 16 lanes hold the row's result.
#pragma unroll
    for (int i = 0; i < 4; ++i) {
        float bd = bestd[i];
        int   bj = bestj[i];
#pragma unroll
        for (int m = 1; m <= 8; m <<= 1) {
            const float od = __shfl_xor(bd, m, 64);
            const int   oj = __shfl_xor(bj, m, 64);
            if (od < bd || (od == bd && oj < bj)) { bd = od; bj = oj; }
        }
        const int row = r0 + tr * 4 + i;
        const float* zp = shz + (tr * 4 + i) * 68 + tc * 4;
        const float4 cv = *(const float4*)(cb + (size_t)bj * 64 + tc * 4);
        const float o0 = zp[0] + (cv.x - zp[0]);
        const float o1 = zp[1] + (cv.y - zp[1]);
        const float o2 = zp[2] + (cv.z - zp[2]);
        const float o3 = zp[3] + (cv.w - zp[3]);
        *(ushort4*)(zq + (size_t)row * 64 + tc * 4) =
            make_ushort4(f2bf(o0), f2bf(o1), f2bf(o2), f2bf(o3));
    }
}

// ---------------------------------------------------------------------------
// GEMM: C[M,N] = A[M,K] * B[N,K]^T + bias.  128x128 tile, 4 waves (64x64),
// BK=32, global_load_lds width=16, 16x16x32 MFMA.
// DT: 1 = fp16 operands, 0 = bf16.  TERMS: 3 = split, 1 = plain.
// OUT: 0 = fp32 Cf, 1 = bf16 Ch, 2 = fp16 split (Ch, Cl).
// r7: XOR in-slot staging/read permutation -> 0 bank conflicts, bit-identical.
// r8: double-buffered 2-phase prefetch.   r9: counted-vmcnt raw-barrier
// schedule (no vmcnt(0) drain in steady state).
template<int DT>
__device__ __forceinline__ floatx4 mfma16(short8 a, short8 b, floatx4 c) {
    if (DT)
        return __builtin_amdgcn_mfma_f32_16x16x32_f16(
            __builtin_bit_cast(half8, a), __builtin_bit_cast(half8, b), c, 0, 0, 0);
    return __builtin_amdgcn_mfma_f32_16x16x32_bf16(a, b, c, 0, 0, 0);
}

template<int DT, int TERMS, int RELU, int OUT>
__global__ __launch_bounds__(256)
void gemm_k(const unsigned short* __restrict__ Ah, const unsigned short* __restrict__ Al,
            const unsigned short* __restrict__ Bh, const unsigned short* __restrict__ Bl,
            const float* __restrict__ bias,
            float* __restrict__ Cf,
            unsigned short* __restrict__ Ch, unsigned short* __restrict__ Cl,
            int M, int N, int K)
{
    __shared__ unsigned short sAh[2][4096], sBh[2][4096];
    __shared__ unsigned short sAl[TERMS >= 3 ? 2 : 1][TERMS >= 3 ? 4096 : 64];
    __shared__ unsigned short sBl[TERMS >= 3 ? 2 : 1][TERMS >= 3 ? 4096 : 64];

    const int t    = threadIdx.x;
    const int wave = t >> 6;
    const int lane = t & 63;
    const int bm = blockIdx.y * 128;
    const int bn = blockIdx.x * 128;
    const int wm = (wave & 1) * 64;
    const int wn = (wave >> 1) * 64;

    floatx4 acc[4][4];
#pragma unroll
    for (int i = 0; i < 4; ++i)
#pragma unroll
        for (int j = 0; j < 4; ++j) acc[i][j] = (floatx4){0.f, 0.f, 0.f, 0.f};

    // staging: lane l -> row l>>2 of the 16-row chunk, k-chunk (l&3)^((l>>3)&3)
    // (4-lane group still covers the same contiguous 64B of one row).
    const int c0 = wave, c1 = wave + 4;
    const int kc  = (lane & 3) ^ ((lane >> 3) & 3);
    const int skb = kc * 8;
    const size_t aoff0 = (size_t)(bm + c0 * 16 + (lane >> 2)) * K + skb;
    const size_t aoff1 = (size_t)(bm + c1 * 16 + (lane >> 2)) * K + skb;
    const size_t boff0 = (size_t)(bn + c0 * 16 + (lane >> 2)) * K + skb;
    const size_t boff1 = (size_t)(bn + c1 * 16 + (lane >> 2)) * K + skb;

    const int fr = lane & 15;
    const int kq = lane >> 4;
    // conflict-free read slot: per 8-lane b128 group, slot%8 covers {0..7}
    const int slot = fr * 4 + (kq ^ ((fr >> 1) & 3));   // holds (row fr, kc kq)

    auto STAGE = [&](int buf, int k0) {
        GLDS16(Ah + aoff0 + k0, sAh[buf] + c0 * 512);
        GLDS16(Ah + aoff1 + k0, sAh[buf] + c1 * 512);
        GLDS16(Bh + boff0 + k0, sBh[buf] + c0 * 512);
        GLDS16(Bh + boff1 + k0, sBh[buf] + c1 * 512);
        if (TERMS >= 3) {
            GLDS16(Al + aoff0 + k0, sAl[buf] + c0 * 512);
            GLDS16(Al + aoff1 + k0, sAl[buf] + c1 * 512);
            GLDS16(Bl + boff0 + k0, sBl[buf] + c0 * 512);
            GLDS16(Bl + boff1 + k0, sBl[buf] + c1 * 512);
        }
    };

    auto COMPUTE = [&](int buf) {
        short8 ah[4], bh[4], al[4], bl[4];
#pragma unroll
        for (int i = 0; i < 4; ++i) {
            const int ao = ((wm >> 4) + i) * 512 + slot * 8;
            const int bo = ((wn >> 4) + i) * 512 + slot * 8;
            ah[i] = *(const short8*)(sAh[buf] + ao);
            bh[i] = *(const short8*)(sBh[buf] + bo);
            if (TERMS >= 3) {
                al[i] = *(const short8*)(sAl[buf] + ao);
                bl[i] = *(const short8*)(sBl[buf] + bo);
            }
        }
#pragma unroll
        for (int i = 0; i < 4; ++i)
#pragma unroll
            for (int j = 0; j < 4; ++j) {
                if (TERMS >= 3) {
                    acc[i][j] = mfma16<DT>(al[i], bh[j], acc[i][j]);
                    acc[i][j] = mfma16<DT>(ah[i], bl[j], acc[i][j]);
                }
                acc[i][j] = mfma16<DT>(ah[i], bh[j], acc[i][j]);
            }
    };

    // counted waits: NLD = loads per STAGE (8 split / 4 plain).
    // "memory" clobber = compiler-level fence: no ds_read hoisting/caching
    // across it (GLDS->LDS writes are invisible to the compiler's dataflow).
    auto WAIT_N = [&]() {
        if constexpr (TERMS >= 3)
            asm volatile("s_waitcnt vmcnt(8)" ::: "memory");
        else
            asm volatile("s_waitcnt vmcnt(4)" ::: "memory");
    };
    auto WAIT_0 = [&]() {
        asm volatile("s_waitcnt vmcnt(0)" ::: "memory");
    };

    // r9 schedule (K % 64 == 0 for all dispatches):
    //   prologue: STAGE(0, 0)
    //   iter:  S1=STAGE(1,k+32); vm(N); bar; COMP(0); bar;
    //          [S2=STAGE(0,k+64); vm(N) | vm(0)]; bar; COMP(1); bar
    // Hazards: read-after-write = per-thread counted wait + pre-COMP barrier;
    // write-after-read = post-COMP barrier before the buffer's next STAGE.
    STAGE(0, 0);
    for (int k0 = 0; k0 < K; k0 += 64) {
        STAGE(1, k0 + 32);                 // k0+32 < K always (K%64==0)
        WAIT_N();                          // STAGE(0,k0) landed (oldest 8)
        __builtin_amdgcn_s_barrier();      // all threads' buf0 data in LDS
        COMPUTE(0);
        __builtin_amdgcn_s_barrier();      // all reads of buf0 done
        if (k0 + 64 < K) {
            STAGE(0, k0 + 64);
            WAIT_N();                      // STAGE(1,k0+32) landed
        } else {
            WAIT_0();                      // tail: drain STAGE(1,k0+32)
        }
        __builtin_amdgcn_s_barrier();      // all threads' buf1 data in LDS
        COMPUTE(1);
        __builtin_amdgcn_s_barrier();      // all reads of buf1 done
    }

    // C/D layout: col = lane&15, row = (lane>>4)*4 + reg
#pragma unroll
    for (int j = 0; j < 4; ++j) {
        const int col = bn + wn + j * 16 + fr;
        const float bv = bias[col];
#pragma unroll
        for (int i = 0; i < 4; ++i) {
#pragma unroll
            for (int rr = 0; rr < 4; ++rr) {
                const int row = bm + wm + i * 16 + kq * 4 + rr;
                float v = acc[i][j][rr] + bv;
                if (RELU) v = fmaxf(v, 0.f);
                const size_t idx = (size_t)row * N + col;
                if (OUT == 0) {
                    Cf[idx] = v;
                } else if (OUT == 1) {
                    Ch[idx] = f2bf(v);
                } else {
                    unsigned short h = f2h(v);
                    Ch[idx] = h;
                    Cl[idx] = f2h(v - h2f(h));
                }
            }
        }
    }
}

// ---------------------------------------------------------------------------
extern "C" void kernel_launch(void* const* d_in, const int* in_sizes, int n_in,
                              void* d_out, int out_size, void* d_ws, size_t ws_size,
                              hipStream_t stream)
{
    const float* x        = (const float*)d_in[0];
    const float* enc0_w   = (const float*)d_in[1];
    const float* enc0_b   = (const float*)d_in[2];
    const float* enc1_w   = (const float*)d_in[3];
    const float* enc1_b   = (const float*)d_in[4];
    const float* z_w      = (const float*)d_in[5];
    const float* z_b      = (const float*)d_in[6];
    const float* codebook = (const float*)d_in[7];
    const float* dec0_w   = (const float*)d_in[8];
    const float* dec0_b   = (const float*)d_in[9];
    const float* dec1_w   = (const float*)d_in[10];
    const float* dec1_b   = (const float*)d_in[11];
    const float* out_w    = (const float*)d_in[12];
    const float* out_b    = (const float*)d_in[13];
    float* xrec = (float*)d_out;

    const size_t MB = 1048576;
    char* ws = (char*)d_ws;
    char* ob = (char*)d_out;

    // x split lives in d_out (dead after enc0; rewritten by out-GEMM)
    unsigned short* xh   = (unsigned short*)(ob);             // [0,32M) of d_out
    unsigned short* xl   = (unsigned short*)(ob + 32 * MB);   // [32M,64M)
    // ws map (peak 50 MB), lifetimes audited disjoint:
    unsigned short* h0h  = (unsigned short*)(ws);             // [0,16M)  enc0->enc1
    unsigned short* h0l  = (unsigned short*)(ws + 16 * MB);   // [16M,32M)
    unsigned short* w0h  = (unsigned short*)(ws + 32 * MB);   // [32M,36M) ->enc0
    unsigned short* w0l  = (unsigned short*)(ws + 36 * MB);   // [36M,40M)
    unsigned short* w1h  = (unsigned short*)(ws + 48 * MB);   // [48M,49M) ->enc1
    unsigned short* w1l  = (unsigned short*)(ws + 49 * MB);   // [49M,50M)
    float*          h1f  = (float*)(ws + 32 * MB);            // [32M,48M) enc1->zgemm (over dead w0)
    // small tensors over dead h0 region (cvt'd after enc1):
    float*          s2   = (float*)(ws);                      // [0,4K)
    float*          zwT  = (float*)(ws + 524288);             // [512K,1M)
    unsigned short* wd0h = (unsigned short*)(ws + 1 * MB);    // [1M,1.25M)
    unsigned short* wd1h = (unsigned short*)(ws + 1572864);   // [1.5M,2.5M)
    unsigned short* woh  = (unsigned short*)(ws + 2621440);   // [2.5M,6.5M)
    float*          zf   = (float*)(ws + 8 * MB);             // [8M,16M)  z->vq
    unsigned short* zq   = (unsigned short*)(ws + 16 * MB);   // [16M,20M) vq->dec0
    unsigned short* d0   = (unsigned short*)(ws + 20 * MB);   // [20M,28M) dec0->dec1
    unsigned short* d1   = (unsigned short*)(ws + 32 * MB);   // [32M,48M) dec1->out (over dead h1f)

    dim3 blk(256);

    cvt_split_h<<<16384, blk, 0, stream>>>(x, xh, xl, 16777216);
    cvt_split_h<<<2048,  blk, 0, stream>>>(enc0_w, w0h, w0l, 2097152);
    cvt_split_h<<<512,   blk, 0, stream>>>(enc1_w, w1h, w1l, 524288);
    // enc0: relu(x @ W0^T + b0) -> fp16-split h0
    gemm_k<1, 3, 1, 2><<<dim3(8, 64), blk, 0, stream>>>(xh, xl, w0h, w0l, enc0_b,
                                                        nullptr, h0h, h0l, 8192, 1024, 2048);
    // enc1: relu(h0 @ W1^T + b1) -> fp32 h1 (no storage quantization)
    gemm_k<1, 3, 1, 0><<<dim3(4, 64), blk, 0, stream>>>(h0h, h0l, w1h, w1l, enc1_b,
                                                        h1f, nullptr, nullptr, 8192, 512, 1024);
    // h0 region dead -> small preps into [0,6.5M)
    prep_s2<<<4, blk, 0, stream>>>(codebook, s2);
    transpose_zw<<<512, blk, 0, stream>>>(z_w, zwT);
    cvt1<<<128, blk, 0, stream>>>(dec0_w, wd0h, 131072);
    cvt1<<<512, blk, 0, stream>>>(dec1_w, wd1h, 524288);
    cvt1<<<2048, blk, 0, stream>>>(out_w, woh, 2097152);
    // z = h1 @ Wz^T + bz, fp32 VALU with pristine weights
    zgemm<<<1024, blk, 0, stream>>>(h1f, zwT, z_b, zf);
    // VQ argmin with np's exact fp32 distance profile + first-index ties
    vq_kernel<<<512, blk, 0, stream>>>(zf, codebook, s2, zq);
    // decoder (plain bf16)
    gemm_k<0, 1, 1, 1><<<dim3(4, 64), blk, 0, stream>>>(zq, nullptr, wd0h, nullptr, dec0_b,
                                                        nullptr, d0, nullptr, 8192, 512, 256);
    gemm_k<0, 1, 1, 1><<<dim3(8, 64), blk, 0, stream>>>(d0, nullptr, wd1h, nullptr, dec1_b,
                                                        nullptr, d1, nullptr, 8192, 1024, 512);
    gemm_k<0, 1, 0, 0><<<dim3(16, 64), blk, 0, stream>>>(d1, nullptr, woh, nullptr, out_b,
                                                         xrec, nullptr, nullptr, 8192, 2048, 1024);
}

// Round 8
// 503.412 us; speedup vs baseline: 1.0169x; 1.0169x over previous
//
#include <hip/hip_runtime.h>
#include <stdint.h>

// ---------------------------------------------------------------------------
// VQ-VAE forward on MI355X (gfx950).  Round 10.
// r4 insight (kept): np's dists = fl(fl(s1+s2) - 2*G) fp32 grid + first-index
// tie-break reproduced bit-exactly; encoder fp16-split MFMA, z-layer fp32
// VALU, decoder bf16 MFMA.
// r7 (kept): XOR in-slot staging/read permutation -> 0 bank conflicts.
// r8 (kept, re-instated): double-buffered 2-phase prefetch with __syncthreads
// (measured 505.7us).  r9 counted-vmcnt was NULL (+6us) — reproduces the
// guide's regime gate: T4 pays only inside an 8-phase interleave; reverted.
// r10: vq_kernel is LDS-issue-bound (reads/FMA=0.125; ~82us model: 8 waves x
// 16 sweeps x 128 ds_read_b128 x 12cy/CU).  Widen sweeps to 128 codes and the
// per-thread tile to 4 rows x 8 codes: reads/FMA -> 0.094 (-25% LDS insts).
// LDS 56.6KB (still 2 blocks/CU); ~200 VGPR -> 2 waves/SIMD (fine, LDS-bound).
// Per-(row,code) fp32 sequence IDENTICAL (independent accumulators; same dot
// order, same dist formula, same ascending-j strict-< scan + 16-lane
// lexicographic reduce) -> bit-exact argmin incl. np tie semantics.
// ---------------------------------------------------------------------------

typedef unsigned int u32;
typedef __attribute__((ext_vector_type(8))) short   short8;  // 8 x 16-bit
typedef __attribute__((ext_vector_type(8))) _Float16 half8;
typedef __attribute__((ext_vector_type(4))) float   floatx4; // MFMA C/D

__device__ __forceinline__ unsigned short f2bf(float f) {    // RNE fp32->bf16
    u32 u = __float_as_uint(f);
    u += 0x7fffu + ((u >> 16) & 1u);
    return (unsigned short)(u >> 16);
}
__device__ __forceinline__ float bf2f(unsigned short h) {
    return __uint_as_float(((u32)h) << 16);
}
__device__ __forceinline__ unsigned short f2h(float f) {     // RNE fp32->fp16
    _Float16 h = (_Float16)f;
    return __builtin_bit_cast(unsigned short, h);
}
__device__ __forceinline__ float h2f(unsigned short u) {
    return (float)__builtin_bit_cast(_Float16, u);
}

#define GLDS16(gp, lp) __builtin_amdgcn_global_load_lds(                      \
    (const __attribute__((address_space(1))) u32*)(const void*)(gp),          \
    (__attribute__((address_space(3))) u32*)(void*)(lp), 16, 0, 0)

// fp32 -> (hi, lo) fp16 split (encoder operands)
__global__ __launch_bounds__(256)
void cvt_split_h(const float* __restrict__ in, unsigned short* __restrict__ hi,
                 unsigned short* __restrict__ lo, int n)
{
    int i = (blockIdx.x * 256 + threadIdx.x) * 4;
    if (i >= n) return;
    const float4 v = *(const float4*)(in + i);
    unsigned short a = f2h(v.x), b = f2h(v.y), c = f2h(v.z), d = f2h(v.w);
    *(ushort4*)(hi + i) = make_ushort4(a, b, c, d);
    *(ushort4*)(lo + i) = make_ushort4(f2h(v.x - h2f(a)), f2h(v.y - h2f(b)),
                                       f2h(v.z - h2f(c)), f2h(v.w - h2f(d)));
}

// fp32 -> bf16 (decoder weights)
__global__ __launch_bounds__(256)
void cvt1(const float* __restrict__ in, unsigned short* __restrict__ hi, int n)
{
    int i = (blockIdx.x * 256 + threadIdx.x) * 4;
    if (i >= n) return;
    const float4 v = *(const float4*)(in + i);
    *(ushort4*)(hi + i) = make_ushort4(f2bf(v.x), f2bf(v.y), f2bf(v.z), f2bf(v.w));
}

// s2[c] = np.sum(codebook[c]**2) with numpy's EXACT pairwise-64 order:
// 8 accumulators over strided elements, then ((r0+r1)+(r2+r3))+((r4+r5)+(r6+r7))
__global__ __launch_bounds__(256)
void prep_s2(const float* __restrict__ cb, float* __restrict__ s2)
{
    int c = blockIdx.x * 256 + threadIdx.x;   // grid 4 -> 1024 codes
    const float* a = cb + (size_t)c * 64;
    float r[8];
#pragma unroll
    for (int j = 0; j < 8; ++j) r[j] = __fmul_rn(a[j], a[j]);
#pragma unroll
    for (int b = 1; b < 8; ++b)
#pragma unroll
        for (int j = 0; j < 8; ++j)
            r[j] = __fadd_rn(r[j], __fmul_rn(a[8 * b + j], a[8 * b + j]));
    float s = __fadd_rn(__fadd_rn(__fadd_rn(r[0], r[1]), __fadd_rn(r[2], r[3])),
                        __fadd_rn(__fadd_rn(r[4], r[5]), __fadd_rn(r[6], r[7])));
    s2[c] = s;
}

// transpose z_w [256,512] -> zwT [512,256] for coalesced VALU GEMM loads
__global__ __launch_bounds__(256)
void transpose_zw(const float* __restrict__ zw, float* __restrict__ zwT)
{
    int i = blockIdx.x * 256 + threadIdx.x;   // grid 512 -> 131072
    int k = i >> 8, c = i & 255;
    zwT[i] = zw[c * 512 + k];
}

// z = h1 @ z_w^T + z_b in fp32 VALU (pristine weights, 4-phase accumulators).
// 8 rows x 256 cols per block; h1 tile staged in LDS.
__global__ __launch_bounds__(256)
void zgemm(const float* __restrict__ h1, const float* __restrict__ zwT,
           const float* __restrict__ zb, float* __restrict__ zf)
{
    __shared__ float sh[8 * 512];
    const int t = threadIdx.x;
    const int r0 = blockIdx.x * 8;            // grid 1024 -> 8192 rows
    const float4* src = (const float4*)(h1 + (size_t)r0 * 512);
    float4* dst = (float4*)sh;
#pragma unroll
    for (int i = 0; i < 4; ++i) dst[t + i * 256] = src[t + i * 256];
    __syncthreads();

    const int col = t;                        // N = 256
    float acc[8][4];
#pragma unroll
    for (int r = 0; r < 8; ++r)
#pragma unroll
        for (int p = 0; p < 4; ++p) acc[r][p] = 0.f;

    for (int k = 0; k < 512; k += 4) {
        float w0 = zwT[(k + 0) * 256 + col];
        float w1 = zwT[(k + 1) * 256 + col];
        float w2 = zwT[(k + 2) * 256 + col];
        float w3 = zwT[(k + 3) * 256 + col];
#pragma unroll
        for (int r = 0; r < 8; ++r) {
            float4 hv = *(const float4*)(sh + r * 512 + k);
            acc[r][0] += hv.x * w0;
            acc[r][1] += hv.y * w1;
            acc[r][2] += hv.z * w2;
            acc[r][3] += hv.w * w3;
        }
    }
    const float bv = zb[col];
#pragma unroll
    for (int r = 0; r < 8; ++r) {
        float s = ((acc[r][0] + acc[r][1]) + (acc[r][2] + acc[r][3])) + bv;
        zf[(size_t)(r0 + r) * 256 + col] = s;
    }
}

// VQ with np's exact fp32 distance profile:
//   dist_j = fl( fl(s1 + s2_j) - 2*G_j ),  s1 = np-pairwise-64 of fl(z_i^2)
// argmin strict-< ascending (np first-index tie-break, incl. exact fp32 ties).
// r10 geometry: block = 64 rows x 1024 codes; 8 sweeps of 128 codes.
// 256 threads = 16 code lanes (tc) x 16 row groups (tr, 4 rows each);
// per-thread tile 4 rows x 8 codes (q=0..7, j = cc*128 + q*16 + tc).
// reads/FMA = 12/128 vs old 8/64 -> 25% fewer ds_read_b128 (LDS-issue-bound).
__global__ __launch_bounds__(256)
void vq_kernel(const float* __restrict__ z, const float* __restrict__ cb,
               const float* __restrict__ s2g, unsigned short* __restrict__ zq)
{
    __shared__ __align__(16) float shz[64 * 68];
    __shared__ __align__(16) float shc[128 * 68];
    __shared__ __align__(16) float shs2[1024];
    __shared__ float shs1[64];

    const int t  = threadIdx.x;
    const int tc = t & 15;        // code lane 0..15
    const int tr = t >> 4;        // row group 0..15 (4 rows each)
    const int r0 = blockIdx.x * 64;   // grid 512 -> 32768 rows

    // stage s2 table (1024 f32)
    *(float4*)(shs2 + t * 4) = *(const float4*)(s2g + t * 4);
    // stage 64 z-rows: thread t -> row t>>2, float4 slots (t&3)+4k
    {
        const int zr = t >> 2, f0 = t & 3;
        const float* src = z + (size_t)(r0 + zr) * 64;
        float* dst = shz + zr * 68;
#pragma unroll
        for (int k = 0; k < 4; ++k) {
            const int f = f0 + 4 * k;
            *(float4*)(dst + f * 4) = *(const float4*)(src + f * 4);
        }
    }
    __syncthreads();

    // s1 per row: numpy pairwise order, contraction-proof (wave 0 only)
    if (t < 64) {
        const float* a = shz + t * 68;
        float r[8];
#pragma unroll
        for (int j = 0; j < 8; ++j) r[j] = __fmul_rn(a[j], a[j]);
#pragma unroll
        for (int b = 1; b < 8; ++b)
#pragma unroll
            for (int j = 0; j < 8; ++j)
                r[j] = __fadd_rn(r[j], __fmul_rn(a[8 * b + j], a[8 * b + j]));
        shs1[t] = __fadd_rn(
            __fadd_rn(__fadd_rn(r[0], r[1]), __fadd_rn(r[2], r[3])),
            __fadd_rn(__fadd_rn(r[4], r[5]), __fadd_rn(r[6], r[7])));
    }
    __syncthreads();

    float s1r[4];
#pragma unroll
    for (int i = 0; i < 4; ++i) s1r[i] = shs1[tr * 4 + i];

    float bestd[4];
    int   bestj[4];
#pragma unroll
    for (int i = 0; i < 4; ++i) { bestd[i] = 3.4e38f; bestj[i] = 0; }

    for (int cc = 0; cc < 8; ++cc) {
        // stage code chunk cc (codes cc*128 .. cc*128+127) — two passes of the
        // original 64-row coalesced pattern (4 lanes = contiguous 64B of a row)
#pragma unroll
        for (int h = 0; h < 2; ++h) {
            const int cr = h * 64 + (t >> 2), f0 = t & 3;
            const float* src = cb + (size_t)(cc * 128 + cr) * 64;
            float* dst = shc + cr * 68;
#pragma unroll
            for (int k = 0; k < 4; ++k) {
                const int f = f0 + 4 * k;
                *(float4*)(dst + f * 4) = *(const float4*)(src + f * 4);
            }
        }
        __syncthreads();

        // 4 rows x 8 codes, accumulators a0..a3 per pair (same order as r4)
        float acc[4][8][4];
#pragma unroll
        for (int i = 0; i < 4; ++i)
#pragma unroll
            for (int q = 0; q < 8; ++q)
#pragma unroll
                for (int p = 0; p < 4; ++p) acc[i][q][p] = 0.f;

#pragma unroll 2
        for (int d = 0; d < 16; ++d) {
            float4 zv[4], cv[8];
#pragma unroll
            for (int i = 0; i < 4; ++i)
                zv[i] = *(const float4*)(shz + (tr * 4 + i) * 68 + d * 4);
#pragma unroll
            for (int q = 0; q < 8; ++q)
                cv[q] = *(const float4*)(shc + (q * 16 + tc) * 68 + d * 4);
#pragma unroll
            for (int i = 0; i < 4; ++i)
#pragma unroll
                for (int q = 0; q < 8; ++q) {
                    acc[i][q][0] += zv[i].x * cv[q].x;
                    acc[i][q][1] += zv[i].y * cv[q].y;
                    acc[i][q][2] += zv[i].z * cv[q].z;
                    acc[i][q][3] += zv[i].w * cv[q].w;
                }
        }

#pragma unroll
        for (int q = 0; q < 8; ++q) {
            const int j = cc * 128 + q * 16 + tc;   // ascending in (cc,q)
            const float s2v = shs2[j];
#pragma unroll
            for (int i = 0; i < 4; ++i) {
                const float g  = (acc[i][q][0] + acc[i][q][1])
                               + (acc[i][q][2] + acc[i][q][3]);
                const float t1 = __fadd_rn(s1r[i], s2v);     // np: (s1+s2) first
                const float dist = __fadd_rn(t1, -(2.0f * g)); // then - 2*G
                if (dist < bestd[i]) { bestd[i] = dist; bestj[i] = j; }
            }
        }
        __syncthreads();
    }

    // reduce across the 16 tc-lanes (lexicographic min on (dist, j));
    // after the xor-butterfly ALL 16 lanes hold the row's result.
#pragma unroll
    for (int i = 0; i < 4; ++i) {
        float bd = bestd[i];
        int   bj = bestj[i];
#pragma unroll
        for (int m = 1; m <= 8; m <<= 1) {
            const float od = __shfl_xor(bd, m, 64);
            const int   oj = __shfl_xor(bj, m, 64);
            if (od < bd || (od == bd && oj < bj)) { bd = od; bj = oj; }
        }
        const int row = r0 + tr * 4 + i;
        const float* zp = shz + (tr * 4 + i) * 68 + tc * 4;
        const float4 cv = *(const float4*)(cb + (size_t)bj * 64 + tc * 4);
        const float o0 = zp[0] + (cv.x - zp[0]);
        const float o1 = zp[1] + (cv.y - zp[1]);
        const float o2 = zp[2] + (cv.z - zp[2]);
        const float o3 = zp[3] + (cv.w - zp[3]);
        *(ushort4*)(zq + (size_t)row * 64 + tc * 4) =
            make_ushort4(f2bf(o0), f2bf(o1), f2bf(o2), f2bf(o3));
    }
}

// ---------------------------------------------------------------------------
// GEMM: C[M,N] = A[M,K] * B[N,K]^T + bias.  128x128 tile, 4 waves (64x64),
// BK=32, global_load_lds width=16, 16x16x32 MFMA.
// DT: 1 = fp16 operands, 0 = bf16.  TERMS: 3 = split, 1 = plain.
// OUT: 0 = fp32 Cf, 1 = bf16 Ch, 2 = fp16 split (Ch, Cl).
// r7: XOR in-slot staging/read permutation -> 0 bank conflicts, bit-identical.
// r8 schedule (re-instated; r9 counted-vmcnt was null on this structure):
// double-buffered 2-phase prefetch, one __syncthreads per half-step.
template<int DT>
__device__ __forceinline__ floatx4 mfma16(short8 a, short8 b, floatx4 c) {
    if (DT)
        return __builtin_amdgcn_mfma_f32_16x16x32_f16(
            __builtin_bit_cast(half8, a), __builtin_bit_cast(half8, b), c, 0, 0, 0);
    return __builtin_amdgcn_mfma_f32_16x16x32_bf16(a, b, c, 0, 0, 0);
}

template<int DT, int TERMS, int RELU, int OUT>
__global__ __launch_bounds__(256)
void gemm_k(const unsigned short* __restrict__ Ah, const unsigned short* __restrict__ Al,
            const unsigned short* __restrict__ Bh, const unsigned short* __restrict__ Bl,
            const float* __restrict__ bias,
            float* __restrict__ Cf,
            unsigned short* __restrict__ Ch, unsigned short* __restrict__ Cl,
            int M, int N, int K)
{
    __shared__ unsigned short sAh[2][4096], sBh[2][4096];
    __shared__ unsigned short sAl[TERMS >= 3 ? 2 : 1][TERMS >= 3 ? 4096 : 64];
    __shared__ unsigned short sBl[TERMS >= 3 ? 2 : 1][TERMS >= 3 ? 4096 : 64];

    const int t    = threadIdx.x;
    const int wave = t >> 6;
    const int lane = t & 63;
    const int bm = blockIdx.y * 128;
    const int bn = blockIdx.x * 128;
    const int wm = (wave & 1) * 64;
    const int wn = (wave >> 1) * 64;

    floatx4 acc[4][4];
#pragma unroll
    for (int i = 0; i < 4; ++i)
#pragma unroll
        for (int j = 0; j < 4; ++j) acc[i][j] = (floatx4){0.f, 0.f, 0.f, 0.f};

    // staging: lane l -> row l>>2 of the 16-row chunk, k-chunk (l&3)^((l>>3)&3)
    // (4-lane group still covers the same contiguous 64B of one row).
    const int c0 = wave, c1 = wave + 4;
    const int kc  = (lane & 3) ^ ((lane >> 3) & 3);
    const int skb = kc * 8;
    const size_t aoff0 = (size_t)(bm + c0 * 16 + (lane >> 2)) * K + skb;
    const size_t aoff1 = (size_t)(bm + c1 * 16 + (lane >> 2)) * K + skb;
    const size_t boff0 = (size_t)(bn + c0 * 16 + (lane >> 2)) * K + skb;
    const size_t boff1 = (size_t)(bn + c1 * 16 + (lane >> 2)) * K + skb;

    const int fr = lane & 15;
    const int kq = lane >> 4;
    // conflict-free read slot: per 8-lane b128 group, slot%8 covers {0..7}
    const int slot = fr * 4 + (kq ^ ((fr >> 1) & 3));   // holds (row fr, kc kq)

    auto STAGE = [&](int buf, int k0) {
        GLDS16(Ah + aoff0 + k0, sAh[buf] + c0 * 512);
        GLDS16(Ah + aoff1 + k0, sAh[buf] + c1 * 512);
        GLDS16(Bh + boff0 + k0, sBh[buf] + c0 * 512);
        GLDS16(Bh + boff1 + k0, sBh[buf] + c1 * 512);
        if (TERMS >= 3) {
            GLDS16(Al + aoff0 + k0, sAl[buf] + c0 * 512);
            GLDS16(Al + aoff1 + k0, sAl[buf] + c1 * 512);
            GLDS16(Bl + boff0 + k0, sBl[buf] + c0 * 512);
            GLDS16(Bl + boff1 + k0, sBl[buf] + c1 * 512);
        }
    };

    auto COMPUTE = [&](int buf) {
        short8 ah[4], bh[4], al[4], bl[4];
#pragma unroll
        for (int i = 0; i < 4; ++i) {
            const int ao = ((wm >> 4) + i) * 512 + slot * 8;
            const int bo = ((wn >> 4) + i) * 512 + slot * 8;
            ah[i] = *(const short8*)(sAh[buf] + ao);
            bh[i] = *(const short8*)(sBh[buf] + bo);
            if (TERMS >= 3) {
                al[i] = *(const short8*)(sAl[buf] + ao);
                bl[i] = *(const short8*)(sBl[buf] + bo);
            }
        }
#pragma unroll
        for (int i = 0; i < 4; ++i)
#pragma unroll
            for (int j = 0; j < 4; ++j) {
                if (TERMS >= 3) {
                    acc[i][j] = mfma16<DT>(al[i], bh[j], acc[i][j]);
                    acc[i][j] = mfma16<DT>(ah[i], bl[j], acc[i][j]);
                }
                acc[i][j] = mfma16<DT>(ah[i], bh[j], acc[i][j]);
            }
    };

    // 2-phase software pipeline, one barrier per K-step.  K % 64 == 0 for all
    // dispatches -> 2x unroll with static buffer indices.
    STAGE(0, 0);
    __syncthreads();
    for (int k0 = 0; k0 < K; k0 += 64) {
        if (k0 + 32 < K) STAGE(1, k0 + 32);
        COMPUTE(0);
        __syncthreads();
        if (k0 + 64 < K) STAGE(0, k0 + 64);
        COMPUTE(1);
        __syncthreads();
    }

    // C/D layout: col = lane&15, row = (lane>>4)*4 + reg
#pragma unroll
    for (int j = 0; j < 4; ++j) {
        const int col = bn + wn + j * 16 + fr;
        const float bv = bias[col];
#pragma unroll
        for (int i = 0; i < 4; ++i) {
#pragma unroll
            for (int rr = 0; rr < 4; ++rr) {
                const int row = bm + wm + i * 16 + kq * 4 + rr;
                float v = acc[i][j][rr] + bv;
                if (RELU) v = fmaxf(v, 0.f);
                const size_t idx = (size_t)row * N + col;
                if (OUT == 0) {
                    Cf[idx] = v;
                } else if (OUT == 1) {
                    Ch[idx] = f2bf(v);
                } else {
                    unsigned short h = f2h(v);
                    Ch[idx] = h;
                    Cl[idx] = f2h(v - h2f(h));
                }
            }
        }
    }
}

// ---------------------------------------------------------------------------
extern "C" void kernel_launch(void* const* d_in, const int* in_sizes, int n_in,
                              void* d_out, int out_size, void* d_ws, size_t ws_size,
                              hipStream_t stream)
{
    const float* x        = (const float*)d_in[0];
    const float* enc0_w   = (const float*)d_in[1];
    const float* enc0_b   = (const float*)d_in[2];
    const float* enc1_w   = (const float*)d_in[3];
    const float* enc1_b   = (const float*)d_in[4];
    const float* z_w      = (const float*)d_in[5];
    const float* z_b      = (const float*)d_in[6];
    const float* codebook = (const float*)d_in[7];
    const float* dec0_w   = (const float*)d_in[8];
    const float* dec0_b   = (const float*)d_in[9];
    const float* dec1_w   = (const float*)d_in[10];
    const float* dec1_b   = (const float*)d_in[11];
    const float* out_w    = (const float*)d_in[12];
    const float* out_b    = (const float*)d_in[13];
    float* xrec = (float*)d_out;

    const size_t MB = 1048576;
    char* ws = (char*)d_ws;
    char* ob = (char*)d_out;

    // x split lives in d_out (dead after enc0; rewritten by out-GEMM)
    unsigned short* xh   = (unsigned short*)(ob);             // [0,32M) of d_out
    unsigned short* xl   = (unsigned short*)(ob + 32 * MB);   // [32M,64M)
    // ws map (peak 50 MB), lifetimes audited disjoint:
    unsigned short* h0h  = (unsigned short*)(ws);             // [0,16M)  enc0->enc1
    unsigned short* h0l  = (unsigned short*)(ws + 16 * MB);   // [16M,32M)
    unsigned short* w0h  = (unsigned short*)(ws + 32 * MB);   // [32M,36M) ->enc0
    unsigned short* w0l  = (unsigned short*)(ws + 36 * MB);   // [36M,40M)
    unsigned short* w1h  = (unsigned short*)(ws + 48 * MB);   // [48M,49M) ->enc1
    unsigned short* w1l  = (unsigned short*)(ws + 49 * MB);   // [49M,50M)
    float*          h1f  = (float*)(ws + 32 * MB);            // [32M,48M) enc1->zgemm (over dead w0)
    // small tensors over dead h0 region (cvt'd after enc1):
    float*          s2   = (float*)(ws);                      // [0,4K)
    float*          zwT  = (float*)(ws + 524288);             // [512K,1M)
    unsigned short* wd0h = (unsigned short*)(ws + 1 * MB);    // [1M,1.25M)
    unsigned short* wd1h = (unsigned short*)(ws + 1572864);   // [1.5M,2.5M)
    unsigned short* woh  = (unsigned short*)(ws + 2621440);   // [2.5M,6.5M)
    float*          zf   = (float*)(ws + 8 * MB);             // [8M,16M)  z->vq
    unsigned short* zq   = (unsigned short*)(ws + 16 * MB);   // [16M,20M) vq->dec0
    unsigned short* d0   = (unsigned short*)(ws + 20 * MB);   // [20M,28M) dec0->dec1
    unsigned short* d1   = (unsigned short*)(ws + 32 * MB);   // [32M,48M) dec1->out (over dead h1f)

    dim3 blk(256);

    cvt_split_h<<<16384, blk, 0, stream>>>(x, xh, xl, 16777216);
    cvt_split_h<<<2048,  blk, 0, stream>>>(enc0_w, w0h, w0l, 2097152);
    cvt_split_h<<<512,   blk, 0, stream>>>(enc1_w, w1h, w1l, 524288);
    // enc0: relu(x @ W0^T + b0) -> fp16-split h0
    gemm_k<1, 3, 1, 2><<<dim3(8, 64), blk, 0, stream>>>(xh, xl, w0h, w0l, enc0_b,
                                                        nullptr, h0h, h0l, 8192, 1024, 2048);
    // enc1: relu(h0 @ W1^T + b1) -> fp32 h1 (no storage quantization)
    gemm_k<1, 3, 1, 0><<<dim3(4, 64), blk, 0, stream>>>(h0h, h0l, w1h, w1l, enc1_b,
                                                        h1f, nullptr, nullptr, 8192, 512, 1024);
    // h0 region dead -> small preps into [0,6.5M)
    prep_s2<<<4, blk, 0, stream>>>(codebook, s2);
    transpose_zw<<<512, blk, 0, stream>>>(z_w, zwT);
    cvt1<<<128, blk, 0, stream>>>(dec0_w, wd0h, 131072);
    cvt1<<<512, blk, 0, stream>>>(dec1_w, wd1h, 524288);
    cvt1<<<2048, blk, 0, stream>>>(out_w, woh, 2097152);
    // z = h1 @ Wz^T + bz, fp32 VALU with pristine weights
    zgemm<<<1024, blk, 0, stream>>>(h1f, zwT, z_b, zf);
    // VQ argmin with np's exact fp32 distance profile + first-index ties
    vq_kernel<<<512, blk, 0, stream>>>(zf, codebook, s2, zq);
    // decoder (plain bf16)
    gemm_k<0, 1, 1, 1><<<dim3(4, 64), blk, 0, stream>>>(zq, nullptr, wd0h, nullptr, dec0_b,
                                                        nullptr, d0, nullptr, 8192, 512, 256);
    gemm_k<0, 1, 1, 1><<<dim3(8, 64), blk, 0, stream>>>(d0, nullptr, wd1h, nullptr, dec1_b,
                                                        nullptr, d1, nullptr, 8192, 1024, 512);
    gemm_k<0, 1, 0, 0><<<dim3(16, 64), blk, 0, stream>>>(d1, nullptr, woh, nullptr, out_b,
                                                         xrec, nullptr, nullptr, 8192, 2048, 1024);
}

// Round 9
// 495.302 us; speedup vs baseline: 1.0335x; 1.0164x over previous
//
#include <hip/hip_runtime.h>
#include <stdint.h>

// ---------------------------------------------------------------------------
// VQ-VAE forward on MI355X (gfx950).  Round 11.
// r4 insight (kept): np's dists = fl(fl(s1+s2) - 2*G) fp32 grid + first-index
// tie-break reproduced bit-exactly; encoder fp16-split MFMA, z-layer fp32
// VALU, decoder bf16 MFMA.  Encoder numerics frozen (tie margin <= 1 ulp).
// r7 (kept): XOR in-slot staging/read permutation -> 0 bank conflicts.
// r8 (kept): 2-phase double-buffered gemm_k (structure ceiling ~115us enc0;
// r9 counted-vmcnt null; r10 enc0 wobble 116->128 = codegen/session noise).
// r10 (kept): vq 4x8 register tile (LDS-issue -25%).
// r11: launch-structure only.  15 serial launches -> 8: all conversions/preps
// fused into ONE mega_prep kernel run up front.  Enabled by workspace remap:
//   h1f -> d_out[0,16M)  (xh dead after enc0; d_out rewritten by out-GEMM)
//   smalls (s2,zwT,wd0h,wd1h,woh) -> ws[40,48M)  (never overwritten now)
//   d1 -> ws[0,16M)      (h0h/zf dead by dec1)
// Lifetime audit (stream-serialized):
//   mega_prep writes: d_out[0,64) xh/xl; ws[32,40) w0; ws[48,50) w1;
//                     ws[40,48) smalls.  All disjoint.
//   enc0:  R xh,xl,w0  W h0h[0,16),h0l[16,32)           (smalls untouched)
//   enc1:  R h0,w1     W h1f=d_out[0,16)                (xh dead)
//   zgemm: R h1f,zwT   W zf=ws[8,16)                    (h0h dead)
//   vq:    R zf,cb,s2  W zq=ws[16,20)                   (h0l dead)
//   dec0:  R zq,wd0h   W d0=ws[20,28)
//   dec1:  R d0,wd1h   W d1=ws[0,16)                    (zf/h0h dead)
//   out:   R d1,woh    W xrec=d_out[0,64)               (h1f dead)
// All per-element arithmetic identical -> bit-exact output.
// ---------------------------------------------------------------------------

typedef unsigned int u32;
typedef __attribute__((ext_vector_type(8))) short   short8;  // 8 x 16-bit
typedef __attribute__((ext_vector_type(8))) _Float16 half8;
typedef __attribute__((ext_vector_type(4))) float   floatx4; // MFMA C/D

__device__ __forceinline__ unsigned short f2bf(float f) {    // RNE fp32->bf16
    u32 u = __float_as_uint(f);
    u += 0x7fffu + ((u >> 16) & 1u);
    return (unsigned short)(u >> 16);
}
__device__ __forceinline__ float bf2f(unsigned short h) {
    return __uint_as_float(((u32)h) << 16);
}
__device__ __forceinline__ unsigned short f2h(float f) {     // RNE fp32->fp16
    _Float16 h = (_Float16)f;
    return __builtin_bit_cast(unsigned short, h);
}
__device__ __forceinline__ float h2f(unsigned short u) {
    return (float)__builtin_bit_cast(_Float16, u);
}

#define GLDS16(gp, lp) __builtin_amdgcn_global_load_lds(                      \
    (const __attribute__((address_space(1))) u32*)(const void*)(gp),          \
    (__attribute__((address_space(3))) u32*)(void*)(lp), 16, 0, 0)

__device__ __forceinline__ void split4(const float* __restrict__ in,
                                       unsigned short* __restrict__ hi,
                                       unsigned short* __restrict__ lo, int i)
{
    const float4 v = *(const float4*)(in + i);
    unsigned short a = f2h(v.x), b = f2h(v.y), c = f2h(v.z), d = f2h(v.w);
    *(ushort4*)(hi + i) = make_ushort4(a, b, c, d);
    *(ushort4*)(lo + i) = make_ushort4(f2h(v.x - h2f(a)), f2h(v.y - h2f(b)),
                                       f2h(v.z - h2f(c)), f2h(v.w - h2f(d)));
}
__device__ __forceinline__ void cvt4(const float* __restrict__ in,
                                     unsigned short* __restrict__ hi, int i)
{
    const float4 v = *(const float4*)(in + i);
    *(ushort4*)(hi + i) = make_ushort4(f2bf(v.x), f2bf(v.y), f2bf(v.z), f2bf(v.w));
}

// One kernel for ALL conversions/preps.  Segment boundaries (blocks):
//   [0,16384)      x split          16777216 floats
//   [16384,18432)  enc0_w split      2097152
//   [18432,18944)  enc1_w split       524288
//   [18944,19072)  dec0_w cvt1        131072
//   [19072,19584)  dec1_w cvt1        524288
//   [19584,21632)  out_w cvt1        2097152
//   [21632,22144)  transpose_zw       131072 scalar items
//   [22144,22148)  prep_s2              1024 codes (numpy pairwise-64 order)
__global__ __launch_bounds__(256)
void mega_prep(const float* __restrict__ x,    unsigned short* __restrict__ xh,
               unsigned short* __restrict__ xl,
               const float* __restrict__ w0,   unsigned short* __restrict__ w0h,
               unsigned short* __restrict__ w0l,
               const float* __restrict__ w1,   unsigned short* __restrict__ w1h,
               unsigned short* __restrict__ w1l,
               const float* __restrict__ dw0,  unsigned short* __restrict__ wd0h,
               const float* __restrict__ dw1,  unsigned short* __restrict__ wd1h,
               const float* __restrict__ ow,   unsigned short* __restrict__ woh,
               const float* __restrict__ zw,   float* __restrict__ zwT,
               const float* __restrict__ cb,   float* __restrict__ s2)
{
    const int b = blockIdx.x;
    const int t = threadIdx.x;
    if (b < 16384) {
        split4(x, xh, xl, (b * 256 + t) * 4);
    } else if (b < 18432) {
        split4(w0, w0h, w0l, ((b - 16384) * 256 + t) * 4);
    } else if (b < 18944) {
        split4(w1, w1h, w1l, ((b - 18432) * 256 + t) * 4);
    } else if (b < 19072) {
        cvt4(dw0, wd0h, ((b - 18944) * 256 + t) * 4);
    } else if (b < 19584) {
        cvt4(dw1, wd1h, ((b - 19072) * 256 + t) * 4);
    } else if (b < 21632) {
        cvt4(ow, woh, ((b - 19584) * 256 + t) * 4);
    } else if (b < 22144) {
        const int i = (b - 21632) * 256 + t;        // zwT[512][256]
        const int k = i >> 8, c = i & 255;
        zwT[i] = zw[c * 512 + k];
    } else {
        const int c = (b - 22144) * 256 + t;        // 1024 codes
        const float* a = cb + (size_t)c * 64;
        float r[8];
#pragma unroll
        for (int j = 0; j < 8; ++j) r[j] = __fmul_rn(a[j], a[j]);
#pragma unroll
        for (int bb = 1; bb < 8; ++bb)
#pragma unroll
            for (int j = 0; j < 8; ++j)
                r[j] = __fadd_rn(r[j], __fmul_rn(a[8 * bb + j], a[8 * bb + j]));
        s2[c] = __fadd_rn(
            __fadd_rn(__fadd_rn(r[0], r[1]), __fadd_rn(r[2], r[3])),
            __fadd_rn(__fadd_rn(r[4], r[5]), __fadd_rn(r[6], r[7])));
    }
}

// z = h1 @ z_w^T + z_b in fp32 VALU (pristine weights, 4-phase accumulators).
// 8 rows x 256 cols per block; h1 tile staged in LDS.
__global__ __launch_bounds__(256)
void zgemm(const float* __restrict__ h1, const float* __restrict__ zwT,
           const float* __restrict__ zb, float* __restrict__ zf)
{
    __shared__ float sh[8 * 512];
    const int t = threadIdx.x;
    const int r0 = blockIdx.x * 8;            // grid 1024 -> 8192 rows
    const float4* src = (const float4*)(h1 + (size_t)r0 * 512);
    float4* dst = (float4*)sh;
#pragma unroll
    for (int i = 0; i < 4; ++i) dst[t + i * 256] = src[t + i * 256];
    __syncthreads();

    const int col = t;                        // N = 256
    float acc[8][4];
#pragma unroll
    for (int r = 0; r < 8; ++r)
#pragma unroll
        for (int p = 0; p < 4; ++p) acc[r][p] = 0.f;

    for (int k = 0; k < 512; k += 4) {
        float w0 = zwT[(k + 0) * 256 + col];
        float w1 = zwT[(k + 1) * 256 + col];
        float w2 = zwT[(k + 2) * 256 + col];
        float w3 = zwT[(k + 3) * 256 + col];
#pragma unroll
        for (int r = 0; r < 8; ++r) {
            float4 hv = *(const float4*)(sh + r * 512 + k);
            acc[r][0] += hv.x * w0;
            acc[r][1] += hv.y * w1;
            acc[r][2] += hv.z * w2;
            acc[r][3] += hv.w * w3;
        }
    }
    const float bv = zb[col];
#pragma unroll
    for (int r = 0; r < 8; ++r) {
        float s = ((acc[r][0] + acc[r][1]) + (acc[r][2] + acc[r][3])) + bv;
        zf[(size_t)(r0 + r) * 256 + col] = s;
    }
}

// VQ with np's exact fp32 distance profile:
//   dist_j = fl( fl(s1 + s2_j) - 2*G_j ),  s1 = np-pairwise-64 of fl(z_i^2)
// argmin strict-< ascending (np first-index tie-break, incl. exact fp32 ties).
// r10 geometry: block = 64 rows x 1024 codes; 8 sweeps of 128 codes; thread
// tile 4 rows x 8 codes (j = cc*128 + q*16 + tc, ascending per thread).
__global__ __launch_bounds__(256)
void vq_kernel(const float* __restrict__ z, const float* __restrict__ cb,
               const float* __restrict__ s2g, unsigned short* __restrict__ zq)
{
    __shared__ __align__(16) float shz[64 * 68];
    __shared__ __align__(16) float shc[128 * 68];
    __shared__ __align__(16) float shs2[1024];
    __shared__ float shs1[64];

    const int t  = threadIdx.x;
    const int tc = t & 15;        // code lane 0..15
    const int tr = t >> 4;        // row group 0..15 (4 rows each)
    const int r0 = blockIdx.x * 64;   // grid 512 -> 32768 rows

    // stage s2 table (1024 f32)
    *(float4*)(shs2 + t * 4) = *(const float4*)(s2g + t * 4);
    // stage 64 z-rows: thread t -> row t>>2, float4 slots (t&3)+4k
    {
        const int zr = t >> 2, f0 = t & 3;
        const float* src = z + (size_t)(r0 + zr) * 64;
        float* dst = shz + zr * 68;
#pragma unroll
        for (int k = 0; k < 4; ++k) {
            const int f = f0 + 4 * k;
            *(float4*)(dst + f * 4) = *(const float4*)(src + f * 4);
        }
    }
    __syncthreads();

    // s1 per row: numpy pairwise order, contraction-proof (wave 0 only)
    if (t < 64) {
        const float* a = shz + t * 68;
        float r[8];
#pragma unroll
        for (int j = 0; j < 8; ++j) r[j] = __fmul_rn(a[j], a[j]);
#pragma unroll
        for (int b = 1; b < 8; ++b)
#pragma unroll
            for (int j = 0; j < 8; ++j)
                r[j] = __fadd_rn(r[j], __fmul_rn(a[8 * b + j], a[8 * b + j]));
        shs1[t] = __fadd_rn(
            __fadd_rn(__fadd_rn(r[0], r[1]), __fadd_rn(r[2], r[3])),
            __fadd_rn(__fadd_rn(r[4], r[5]), __fadd_rn(r[6], r[7])));
    }
    __syncthreads();

    float s1r[4];
#pragma unroll
    for (int i = 0; i < 4; ++i) s1r[i] = shs1[tr * 4 + i];

    float bestd[4];
    int   bestj[4];
#pragma unroll
    for (int i = 0; i < 4; ++i) { bestd[i] = 3.4e38f; bestj[i] = 0; }

    for (int cc = 0; cc < 8; ++cc) {
        // stage code chunk cc (codes cc*128 .. cc*128+127) — two passes of the
        // original 64-row coalesced pattern (4 lanes = contiguous 64B of a row)
#pragma unroll
        for (int h = 0; h < 2; ++h) {
            const int cr = h * 64 + (t >> 2), f0 = t & 3;
            const float* src = cb + (size_t)(cc * 128 + cr) * 64;
            float* dst = shc + cr * 68;
#pragma unroll
            for (int k = 0; k < 4; ++k) {
                const int f = f0 + 4 * k;
                *(float4*)(dst + f * 4) = *(const float4*)(src + f * 4);
            }
        }
        __syncthreads();

        // 4 rows x 8 codes, accumulators a0..a3 per pair (same order as r4)
        float acc[4][8][4];
#pragma unroll
        for (int i = 0; i < 4; ++i)
#pragma unroll
            for (int q = 0; q < 8; ++q)
#pragma unroll
                for (int p = 0; p < 4; ++p) acc[i][q][p] = 0.f;

#pragma unroll 2
        for (int d = 0; d < 16; ++d) {
            float4 zv[4], cv[8];
#pragma unroll
            for (int i = 0; i < 4; ++i)
                zv[i] = *(const float4*)(shz + (tr * 4 + i) * 68 + d * 4);
#pragma unroll
            for (int q = 0; q < 8; ++q)
                cv[q] = *(const float4*)(shc + (q * 16 + tc) * 68 + d * 4);
#pragma unroll
            for (int i = 0; i < 4; ++i)
#pragma unroll
                for (int q = 0; q < 8; ++q) {
                    acc[i][q][0] += zv[i].x * cv[q].x;
                    acc[i][q][1] += zv[i].y * cv[q].y;
                    acc[i][q][2] += zv[i].z * cv[q].z;
                    acc[i][q][3] += zv[i].w * cv[q].w;
                }
        }

#pragma unroll
        for (int q = 0; q < 8; ++q) {
            const int j = cc * 128 + q * 16 + tc;   // ascending in (cc,q)
            const float s2v = shs2[j];
#pragma unroll
            for (int i = 0; i < 4; ++i) {
                const float g  = (acc[i][q][0] + acc[i][q][1])
                               + (acc[i][q][2] + acc[i][q][3]);
                const float t1 = __fadd_rn(s1r[i], s2v);     // np: (s1+s2) first
                const float dist = __fadd_rn(t1, -(2.0f * g)); // then - 2*G
                if (dist < bestd[i]) { bestd[i] = dist; bestj[i] = j; }
            }
        }
        __syncthreads();
    }

    // reduce across the 16 tc-lanes (lexicographic min on (dist, j));
    // after the xor-butterfly ALL 16 lanes hold the row's result.
#pragma unroll
    for (int i = 0; i < 4; ++i) {
        float bd = bestd[i];
        int   bj = bestj[i];
#pragma unroll
        for (int m = 1; m <= 8; m <<= 1) {
            const float od = __shfl_xor(bd, m, 64);
            const int   oj = __shfl_xor(bj, m, 64);
            if (od < bd || (od == bd && oj < bj)) { bd = od; bj = oj; }
        }
        const int row = r0 + tr * 4 + i;
        const float* zp = shz + (tr * 4 + i) * 68 + tc * 4;
        const float4 cv = *(const float4*)(cb + (size_t)bj * 64 + tc * 4);
        const float o0 = zp[0] + (cv.x - zp[0]);
        const float o1 = zp[1] + (cv.y - zp[1]);
        const float o2 = zp[2] + (cv.z - zp[2]);
        const float o3 = zp[3] + (cv.w - zp[3]);
        *(ushort4*)(zq + (size_t)row * 64 + tc * 4) =
            make_ushort4(f2bf(o0), f2bf(o1), f2bf(o2), f2bf(o3));
    }
}

// ---------------------------------------------------------------------------
// GEMM: C[M,N] = A[M,K] * B[N,K]^T + bias.  128x128 tile, 4 waves (64x64),
// BK=32, global_load_lds width=16, 16x16x32 MFMA.
// DT: 1 = fp16 operands, 0 = bf16.  TERMS: 3 = split, 1 = plain.
// OUT: 0 = fp32 Cf, 1 = bf16 Ch, 2 = fp16 split (Ch, Cl).
// r7: XOR in-slot staging/read permutation -> 0 bank conflicts, bit-identical.
// r8 schedule: double-buffered 2-phase prefetch, one __syncthreads/half-step.
template<int DT>
__device__ __forceinline__ floatx4 mfma16(short8 a, short8 b, floatx4 c) {
    if (DT)
        return __builtin_amdgcn_mfma_f32_16x16x32_f16(
            __builtin_bit_cast(half8, a), __builtin_bit_cast(half8, b), c, 0, 0, 0);
    return __builtin_amdgcn_mfma_f32_16x16x32_bf16(a, b, c, 0, 0, 0);
}

template<int DT, int TERMS, int RELU, int OUT>
__global__ __launch_bounds__(256)
void gemm_k(const unsigned short* __restrict__ Ah, const unsigned short* __restrict__ Al,
            const unsigned short* __restrict__ Bh, const unsigned short* __restrict__ Bl,
            const float* __restrict__ bias,
            float* __restrict__ Cf,
            unsigned short* __restrict__ Ch, unsigned short* __restrict__ Cl,
            int M, int N, int K)
{
    __shared__ unsigned short sAh[2][4096], sBh[2][4096];
    __shared__ unsigned short sAl[TERMS >= 3 ? 2 : 1][TERMS >= 3 ? 4096 : 64];
    __shared__ unsigned short sBl[TERMS >= 3 ? 2 : 1][TERMS >= 3 ? 4096 : 64];

    const int t    = threadIdx.x;
    const int wave = t >> 6;
    const int lane = t & 63;
    const int bm = blockIdx.y * 128;
    const int bn = blockIdx.x * 128;
    const int wm = (wave & 1) * 64;
    const int wn = (wave >> 1) * 64;

    floatx4 acc[4][4];
#pragma unroll
    for (int i = 0; i < 4; ++i)
#pragma unroll
        for (int j = 0; j < 4; ++j) acc[i][j] = (floatx4){0.f, 0.f, 0.f, 0.f};

    // staging: lane l -> row l>>2 of the 16-row chunk, k-chunk (l&3)^((l>>3)&3)
    // (4-lane group still covers the same contiguous 64B of one row).
    const int c0 = wave, c1 = wave + 4;
    const int kc  = (lane & 3) ^ ((lane >> 3) & 3);
    const int skb = kc * 8;
    const size_t aoff0 = (size_t)(bm + c0 * 16 + (lane >> 2)) * K + skb;
    const size_t aoff1 = (size_t)(bm + c1 * 16 + (lane >> 2)) * K + skb;
    const size_t boff0 = (size_t)(bn + c0 * 16 + (lane >> 2)) * K + skb;
    const size_t boff1 = (size_t)(bn + c1 * 16 + (lane >> 2)) * K + skb;

    const int fr = lane & 15;
    const int kq = lane >> 4;
    // conflict-free read slot: per 8-lane b128 group, slot%8 covers {0..7}
    const int slot = fr * 4 + (kq ^ ((fr >> 1) & 3));   // holds (row fr, kc kq)

    auto STAGE = [&](int buf, int k0) {
        GLDS16(Ah + aoff0 + k0, sAh[buf] + c0 * 512);
        GLDS16(Ah + aoff1 + k0, sAh[buf] + c1 * 512);
        GLDS16(Bh + boff0 + k0, sBh[buf] + c0 * 512);
        GLDS16(Bh + boff1 + k0, sBh[buf] + c1 * 512);
        if (TERMS >= 3) {
            GLDS16(Al + aoff0 + k0, sAl[buf] + c0 * 512);
            GLDS16(Al + aoff1 + k0, sAl[buf] + c1 * 512);
            GLDS16(Bl + boff0 + k0, sBl[buf] + c0 * 512);
            GLDS16(Bl + boff1 + k0, sBl[buf] + c1 * 512);
        }
    };

    auto COMPUTE = [&](int buf) {
        short8 ah[4], bh[4], al[4], bl[4];
#pragma unroll
        for (int i = 0; i < 4; ++i) {
            const int ao = ((wm >> 4) + i) * 512 + slot * 8;
            const int bo = ((wn >> 4) + i) * 512 + slot * 8;
            ah[i] = *(const short8*)(sAh[buf] + ao);
            bh[i] = *(const short8*)(sBh[buf] + bo);
            if (TERMS >= 3) {
                al[i] = *(const short8*)(sAl[buf] + ao);
                bl[i] = *(const short8*)(sBl[buf] + bo);
            }
        }
#pragma unroll
        for (int i = 0; i < 4; ++i)
#pragma unroll
            for (int j = 0; j < 4; ++j) {
                if (TERMS >= 3) {
                    acc[i][j] = mfma16<DT>(al[i], bh[j], acc[i][j]);
                    acc[i][j] = mfma16<DT>(ah[i], bl[j], acc[i][j]);
                }
                acc[i][j] = mfma16<DT>(ah[i], bh[j], acc[i][j]);
            }
    };

    // 2-phase software pipeline, one barrier per K-step.  K % 64 == 0 for all
    // dispatches -> 2x unroll with static buffer indices.
    STAGE(0, 0);
    __syncthreads();
    for (int k0 = 0; k0 < K; k0 += 64) {
        if (k0 + 32 < K) STAGE(1, k0 + 32);
        COMPUTE(0);
        __syncthreads();
        if (k0 + 64 < K) STAGE(0, k0 + 64);
        COMPUTE(1);
        __syncthreads();
    }

    // C/D layout: col = lane&15, row = (lane>>4)*4 + reg
#pragma unroll
    for (int j = 0; j < 4; ++j) {
        const int col = bn + wn + j * 16 + fr;
        const float bv = bias[col];
#pragma unroll
        for (int i = 0; i < 4; ++i) {
#pragma unroll
            for (int rr = 0; rr < 4; ++rr) {
                const int row = bm + wm + i * 16 + kq * 4 + rr;
                float v = acc[i][j][rr] + bv;
                if (RELU) v = fmaxf(v, 0.f);
                const size_t idx = (size_t)row * N + col;
                if (OUT == 0) {
                    Cf[idx] = v;
                } else if (OUT == 1) {
                    Ch[idx] = f2bf(v);
                } else {
                    unsigned short h = f2h(v);
                    Ch[idx] = h;
                    Cl[idx] = f2h(v - h2f(h));
                }
            }
        }
    }
}

// ---------------------------------------------------------------------------
extern "C" void kernel_launch(void* const* d_in, const int* in_sizes, int n_in,
                              void* d_out, int out_size, void* d_ws, size_t ws_size,
                              hipStream_t stream)
{
    const float* x        = (const float*)d_in[0];
    const float* enc0_w   = (const float*)d_in[1];
    const float* enc0_b   = (const float*)d_in[2];
    const float* enc1_w   = (const float*)d_in[3];
    const float* enc1_b   = (const float*)d_in[4];
    const float* z_w      = (const float*)d_in[5];
    const float* z_b      = (const float*)d_in[6];
    const float* codebook = (const float*)d_in[7];
    const float* dec0_w   = (const float*)d_in[8];
    const float* dec0_b   = (const float*)d_in[9];
    const float* dec1_w   = (const float*)d_in[10];
    const float* dec1_b   = (const float*)d_in[11];
    const float* out_w    = (const float*)d_in[12];
    const float* out_b    = (const float*)d_in[13];
    float* xrec = (float*)d_out;

    const size_t MB = 1048576;
    char* ws = (char*)d_ws;
    char* ob = (char*)d_out;

    // d_out map: xh [0,32M), xl [32M,64M) (dead after enc0);
    //            h1f [0,16M) (enc1->zgemm); xrec (out-GEMM, full 64M).
    unsigned short* xh   = (unsigned short*)(ob);
    unsigned short* xl   = (unsigned short*)(ob + 32 * MB);
    float*          h1f  = (float*)(ob);                      // over dead xh
    // ws map (peak 50 MB), lifetimes audited disjoint (see header):
    unsigned short* h0h  = (unsigned short*)(ws);             // [0,16M)  enc0->enc1
    unsigned short* h0l  = (unsigned short*)(ws + 16 * MB);   // [16M,32M)
    unsigned short* w0h  = (unsigned short*)(ws + 32 * MB);   // [32M,36M) ->enc0
    unsigned short* w0l  = (unsigned short*)(ws + 36 * MB);   // [36M,40M)
    float*          s2   = (float*)(ws + 40 * MB);            // [40M,+4K)
    float*          zwT  = (float*)(ws + 41 * MB);            // [41M,41.5M)
    unsigned short* wd0h = (unsigned short*)(ws + 42 * MB);   // [42M,42.25M)
    unsigned short* wd1h = (unsigned short*)(ws + 43 * MB);   // [43M,44M)
    unsigned short* woh  = (unsigned short*)(ws + 44 * MB);   // [44M,48M)
    unsigned short* w1h  = (unsigned short*)(ws + 48 * MB);   // [48M,49M) ->enc1
    unsigned short* w1l  = (unsigned short*)(ws + 49 * MB);   // [49M,50M)
    float*          zf   = (float*)(ws + 8 * MB);             // [8M,16M)  z->vq (h0h dead)
    unsigned short* zq   = (unsigned short*)(ws + 16 * MB);   // [16M,20M) vq->dec0 (h0l dead)
    unsigned short* d0   = (unsigned short*)(ws + 20 * MB);   // [20M,28M) dec0->dec1
    unsigned short* d1   = (unsigned short*)(ws);             // [0,16M)   dec1->out (zf/h0h dead)

    dim3 blk(256);

    // 1. all conversions + preps in one launch (22148 blocks)
    mega_prep<<<22148, blk, 0, stream>>>(x, xh, xl,
                                         enc0_w, w0h, w0l,
                                         enc1_w, w1h, w1l,
                                         dec0_w, wd0h,
                                         dec1_w, wd1h,
                                         out_w, woh,
                                         z_w, zwT,
                                         codebook, s2);
    // 2. enc0: relu(x @ W0^T + b0) -> fp16-split h0
    gemm_k<1, 3, 1, 2><<<dim3(8, 64), blk, 0, stream>>>(xh, xl, w0h, w0l, enc0_b,
                                                        nullptr, h0h, h0l, 8192, 1024, 2048);
    // 3. enc1: relu(h0 @ W1^T + b1) -> fp32 h1 (in d_out; xh dead)
    gemm_k<1, 3, 1, 0><<<dim3(4, 64), blk, 0, stream>>>(h0h, h0l, w1h, w1l, enc1_b,
                                                        h1f, nullptr, nullptr, 8192, 512, 1024);
    // 4. z = h1 @ Wz^T + bz, fp32 VALU with pristine weights
    zgemm<<<1024, blk, 0, stream>>>(h1f, zwT, z_b, zf);
    // 5. VQ argmin with np's exact fp32 distance profile + first-index ties
    vq_kernel<<<512, blk, 0, stream>>>(zf, codebook, s2, zq);
    // 6-8. decoder (plain bf16)
    gemm_k<0, 1, 1, 1><<<dim3(4, 64), blk, 0, stream>>>(zq, nullptr, wd0h, nullptr, dec0_b,
                                                        nullptr, d0, nullptr, 8192, 512, 256);
    gemm_k<0, 1, 1, 1><<<dim3(8, 64), blk, 0, stream>>>(d0, nullptr, wd1h, nullptr, dec1_b,
                                                        nullptr, d1, nullptr, 8192, 1024, 512);
    gemm_k<0, 1, 0, 0><<<dim3(16, 64), blk, 0, stream>>>(d1, nullptr, woh, nullptr, out_b,
                                                         xrec, nullptr, nullptr, 8192, 2048, 1024);
}